// Round 12
// baseline (212.590 us; speedup 1.0000x reference)
//
#include <hip/hip_runtime.h>

typedef unsigned short u16;
typedef __bf16 bf16_t;
typedef bf16_t bf16x8 __attribute__((ext_vector_type(8)));
typedef float f32x4 __attribute__((ext_vector_type(4)));
typedef float f32x16 __attribute__((ext_vector_type(16)));
typedef u16 u16x8 __attribute__((ext_vector_type(8)));
typedef u16 u16x4 __attribute__((ext_vector_type(4)));
typedef unsigned uint2v __attribute__((ext_vector_type(2)));

#define B_     4
#define N_     2048
#define DIM_   1024
#define HEADS_ 16
#define DH_    64
#define INNER_ 1024
#define QKV3_  3072
#define SCALE_ 0.125f
#define LOG2E_ 1.44269504089f

__device__ __forceinline__ u16 f2bf(float f) {
  union { float f; unsigned u; } v; v.f = f;
  unsigned r = v.u + 0x7FFFu + ((v.u >> 16) & 1u);
  return (u16)(r >> 16);
}
__device__ __forceinline__ u16 bfbits(float f) {
  bf16_t b = (bf16_t)f;               // RNE; pairs into v_cvt_pk_bf16_f32
  return __builtin_bit_cast(u16, b);
}
__device__ __forceinline__ unsigned packbf(float lo, float hi) {
  return (unsigned)bfbits(lo) | ((unsigned)bfbits(hi) << 16);
}

#if __has_builtin(__builtin_amdgcn_exp2f)
#define EXP2F(x) __builtin_amdgcn_exp2f(x)
#else
#define EXP2F(x) __expf((x) * 0.69314718056f)
#endif

// async global->LDS, 16B per lane; LDS dest = wave-uniform base + lane*16
typedef __attribute__((address_space(1))) const unsigned int ga_u32;
typedef __attribute__((address_space(3))) unsigned int ls_u32;
__device__ __forceinline__ void gload16(const void* g, void* l) {
  __builtin_amdgcn_global_load_lds((ga_u32*)g, (ls_u32*)l, 16, 0, 0);
}

// ---------------- x fp32 -> bf16 (vectorized, G13) ----------------
__global__ __launch_bounds__(256) void cvt_f32_bf16(const float* __restrict__ in,
                                                    u16* __restrict__ out, int n8) {
  int i = blockIdx.x * 256 + threadIdx.x;
  if (i < n8) {
    const float4* p = (const float4*)(in + (size_t)i * 8);
    float4 a = p[0], b = p[1];
    u16x8 o;
    o[0] = f2bf(a.x); o[1] = f2bf(a.y); o[2] = f2bf(a.z); o[3] = f2bf(a.w);
    o[4] = f2bf(b.x); o[5] = f2bf(b.y); o[6] = f2bf(b.z); o[7] = f2bf(b.w);
    *(u16x8*)(out + (size_t)i * 8) = o;
  }
}

// ---------------- w [K][N] fp32 -> wT [N][K] bf16 ----------------
__global__ __launch_bounds__(256) void transp_w(const float* __restrict__ in,
                                                u16* __restrict__ out, int Kd, int Nd) {
  __shared__ float t[32][33];
  int n0 = blockIdx.x * 32, k0 = blockIdx.y * 32;
  int tx = threadIdx.x & 31, ty = threadIdx.x >> 5;   // 256 threads: 32x8
#pragma unroll
  for (int i = 0; i < 4; i++)
    t[ty + i * 8][tx] = in[(size_t)(k0 + ty + i * 8) * Nd + n0 + tx];
  __syncthreads();
#pragma unroll
  for (int i = 0; i < 4; i++)
    out[(size_t)(n0 + ty + i * 8) * Kd + k0 + tx] = f2bf(t[tx][ty + i * 8]);
}

// ---------------- fused QKV GEMM (128x128, reverted from failed 256^2) ----------------
// 4 waves (2x2). 2-buffer COUNTED-vmcnt pipeline: vmcnt(8); barrier; compute;
// barrier; issue ks+2. Epilogue scatters Q plain, K/V slot-major tiled.
__global__ __launch_bounds__(256) void gemm_qkv(const u16* __restrict__ A,
                                                const u16* __restrict__ BT,
                                                u16* __restrict__ qbuf,
                                                u16* __restrict__ ktiled,
                                                u16* __restrict__ vtiled,
                                                int M, int N, int K) {
  __shared__ alignas(16) u16 ldsA[2][128 * 64];
  __shared__ alignas(16) u16 ldsB[2][128 * 64];
  const int tid = threadIdx.x;
  const int lane = tid & 63, wid = tid >> 6;
  const int l16 = lane & 15, lg = lane >> 4;

  int bid = blockIdx.x;
  const int cpx = gridDim.x >> 3;            // chunk per XCD (grid % 8 == 0)
  bid = (bid & 7) * cpx + (bid >> 3);        // T1 bijective XCD swizzle

  const int ntiles = N >> 7;
  const int tm = bid / ntiles, tn = bid % ntiles;
  const int m0 = tm << 7, n0 = tn << 7;
  const int wr = wid >> 1, wc = wid & 1;

  const int srow_in = lane >> 3;
  const int soff = ((lane & 7) ^ srow_in) * 8;

  f32x4 acc[4][4];
#pragma unroll
  for (int i = 0; i < 4; i++)
#pragma unroll
    for (int j = 0; j < 4; j++) acc[i][j] = f32x4{0.f, 0.f, 0.f, 0.f};

  const int KSTEPS = K >> 6;

#define GSTAGE_(kk, buf)                                                           \
  do {                                                                             \
    const int k1_ = (kk) << 6;                                                     \
    char* bA_ = (char*)&ldsA[(buf)][0];                                            \
    char* bB_ = (char*)&ldsB[(buf)][0];                                            \
    _Pragma("unroll")                                                              \
    for (int i_ = 0; i_ < 4; i_++) {                                               \
      const int rb_ = wid * 32 + i_ * 8;                                           \
      gload16(A  + (size_t)(m0 + rb_ + srow_in) * K + k1_ + soff, bA_ + rb_ * 128);\
      gload16(BT + (size_t)(n0 + rb_ + srow_in) * K + k1_ + soff, bB_ + rb_ * 128);\
    }                                                                              \
  } while (0)

  GSTAGE_(0, 0);
  GSTAGE_(1, 1);

  for (int ks = 0; ks < KSTEPS; ks++) {
    if (ks + 1 < KSTEPS) asm volatile("s_waitcnt vmcnt(8)" ::: "memory");
    else                 asm volatile("s_waitcnt vmcnt(0)" ::: "memory");
    __builtin_amdgcn_s_barrier();

    const char* cA = (const char*)&ldsA[ks & 1][0];
    const char* cB = (const char*)&ldsB[ks & 1][0];

    bf16x8 bf[4][2];
#pragma unroll
    for (int n = 0; n < 4; n++) {
      int row = wc * 64 + n * 16 + l16;
      int rb = row * 128, swz = (row & 7) << 4;
      bf[n][0] = *(const bf16x8*)(cB + rb + ((lg * 16) ^ swz));
      bf[n][1] = *(const bf16x8*)(cB + rb + ((64 + lg * 16) ^ swz));
    }
    __builtin_amdgcn_s_setprio(1);
#pragma unroll
    for (int mm = 0; mm < 4; mm++) {
      int row = wr * 64 + mm * 16 + l16;
      int rb = row * 128, swz = (row & 7) << 4;
      bf16x8 af0 = *(const bf16x8*)(cA + rb + ((lg * 16) ^ swz));
      bf16x8 af1 = *(const bf16x8*)(cA + rb + ((64 + lg * 16) ^ swz));
#pragma unroll
      for (int n = 0; n < 4; n++) {
        acc[mm][n] = __builtin_amdgcn_mfma_f32_16x16x32_bf16(af0, bf[n][0], acc[mm][n], 0, 0, 0);
        acc[mm][n] = __builtin_amdgcn_mfma_f32_16x16x32_bf16(af1, bf[n][1], acc[mm][n], 0, 0, 0);
      }
    }
    __builtin_amdgcn_s_setprio(0);

    __builtin_amdgcn_s_barrier();
    if (ks + 2 < KSTEPS) GSTAGE_(ks + 2, ks & 1);
  }
#undef GSTAGE_

  const int seg = n0 >> 10;   // 0=Q, 1=K, 2=V (uniform per block)
#pragma unroll
  for (int mm = 0; mm < 4; mm++) {
#pragma unroll
    for (int nn = 0; nn < 4; nn++) {
      const int row = m0 + wr * 64 + mm * 16 + lg * 4;
      const int col = n0 + wc * 64 + nn * 16 + l16;
      if (seg == 0) {
#pragma unroll
        for (int j = 0; j < 4; j++)
          qbuf[(size_t)(row + j) * INNER_ + col] = f2bf(acc[mm][nn][j]);
      } else if (seg == 1) {
        const int kd = col - 1024;
        const int h = kd >> 6, s = (kd >> 3) & 7, e = kd & 7;
#pragma unroll
        for (int j = 0; j < 4; j++) {
          const int rr = row + j;
          const int b = rr >> 11, n = rr & (N_ - 1);
          ktiled[(((size_t)(b * HEADS_ + h) * 32 + (n >> 6)) << 12) +
                 (s << 9) + ((n & 63) << 3) + e] = f2bf(acc[mm][nn][j]);
        }
      } else {
        const int vd = col - 2048;
        const int h = vd >> 6, d = vd & 63;
#pragma unroll
        for (int j = 0; j < 4; j++) {
          const int rr = row + j;
          const int b = rr >> 11, n = rr & (N_ - 1);
          vtiled[(((size_t)(b * HEADS_ + h) * 32 + (n >> 6)) << 12) +
                 (((n >> 3) & 7) << 9) + (d << 3) + (n & 7)] = f2bf(acc[mm][nn][j]);
        }
      }
    }
  }
}

// ---------------- GEMM2: C[M][N] = A @ BT^T + bias (f32 out), 128^2 tile ----------------
__global__ __launch_bounds__(256) void gemm_bt(const u16* __restrict__ A,
                                               const u16* __restrict__ BT,
                                               float* __restrict__ Cp,
                                               const float* __restrict__ bias,
                                               int M, int N, int K) {
  __shared__ alignas(16) u16 ldsA[2][128 * 64];
  __shared__ alignas(16) u16 ldsB[2][128 * 64];
  const int tid = threadIdx.x;
  const int lane = tid & 63, wid = tid >> 6;
  const int l16 = lane & 15, lg = lane >> 4;

  int bid = blockIdx.x;
  const int cpx = gridDim.x >> 3;
  bid = (bid & 7) * cpx + (bid >> 3);

  const int ntiles = N >> 7;
  const int tm = bid / ntiles, tn = bid % ntiles;
  const int m0 = tm << 7, n0 = tn << 7;
  const int wr = wid >> 1, wc = wid & 1;

  const int srow_in = lane >> 3;
  const int soff = ((lane & 7) ^ srow_in) * 8;

  f32x4 acc[4][4];
#pragma unroll
  for (int i = 0; i < 4; i++)
#pragma unroll
    for (int j = 0; j < 4; j++) acc[i][j] = f32x4{0.f, 0.f, 0.f, 0.f};

  const int KSTEPS = K >> 6;

#define GSTAGE_(kk, buf)                                                           \
  do {                                                                             \
    const int k1_ = (kk) << 6;                                                     \
    char* bA_ = (char*)&ldsA[(buf)][0];                                            \
    char* bB_ = (char*)&ldsB[(buf)][0];                                            \
    _Pragma("unroll")                                                              \
    for (int i_ = 0; i_ < 4; i_++) {                                               \
      const int rb_ = wid * 32 + i_ * 8;                                           \
      gload16(A  + (size_t)(m0 + rb_ + srow_in) * K + k1_ + soff, bA_ + rb_ * 128);\
      gload16(BT + (size_t)(n0 + rb_ + srow_in) * K + k1_ + soff, bB_ + rb_ * 128);\
    }                                                                              \
  } while (0)

  GSTAGE_(0, 0);
  GSTAGE_(1, 1);

  for (int ks = 0; ks < KSTEPS; ks++) {
    if (ks + 1 < KSTEPS) asm volatile("s_waitcnt vmcnt(8)" ::: "memory");
    else                 asm volatile("s_waitcnt vmcnt(0)" ::: "memory");
    __builtin_amdgcn_s_barrier();

    const char* cA = (const char*)&ldsA[ks & 1][0];
    const char* cB = (const char*)&ldsB[ks & 1][0];

    bf16x8 bf[4][2];
#pragma unroll
    for (int n = 0; n < 4; n++) {
      int row = wc * 64 + n * 16 + l16;
      int rb = row * 128, swz = (row & 7) << 4;
      bf[n][0] = *(const bf16x8*)(cB + rb + ((lg * 16) ^ swz));
      bf[n][1] = *(const bf16x8*)(cB + rb + ((64 + lg * 16) ^ swz));
    }
    __builtin_amdgcn_s_setprio(1);
#pragma unroll
    for (int mm = 0; mm < 4; mm++) {
      int row = wr * 64 + mm * 16 + l16;
      int rb = row * 128, swz = (row & 7) << 4;
      bf16x8 af0 = *(const bf16x8*)(cA + rb + ((lg * 16) ^ swz));
      bf16x8 af1 = *(const bf16x8*)(cA + rb + ((64 + lg * 16) ^ swz));
#pragma unroll
      for (int n = 0; n < 4; n++) {
        acc[mm][n] = __builtin_amdgcn_mfma_f32_16x16x32_bf16(af0, bf[n][0], acc[mm][n], 0, 0, 0);
        acc[mm][n] = __builtin_amdgcn_mfma_f32_16x16x32_bf16(af1, bf[n][1], acc[mm][n], 0, 0, 0);
      }
    }
    __builtin_amdgcn_s_setprio(0);

    __builtin_amdgcn_s_barrier();
    if (ks + 2 < KSTEPS) GSTAGE_(ks + 2, ks & 1);
  }
#undef GSTAGE_

#pragma unroll
  for (int mm = 0; mm < 4; mm++) {
#pragma unroll
    for (int n = 0; n < 4; n++) {
      int row = m0 + wr * 64 + mm * 16 + lg * 4;
      int col = n0 + wc * 64 + n * 16 + l16;
#pragma unroll
      for (int j = 0; j < 4; j++)
        Cp[(size_t)(row + j) * N + col] = acc[mm][n][j] + bias[col];
    }
  }
}

// ---------------- Flash attention (v10: LDS-free, K/V direct from L1/L2) ----------------
// 512 blocks (XCD-swizzled) x 512 threads (8 waves). Wave owns 32 q; QBLK=256.
// K/V are slot-major tiled in global: every fragment load is a fully-coalesced
// 16 B/lane global_load_dwordx4. All 8 waves of a block read the SAME 8 KB tile
// (L1-resident after first touch); the 8 blocks of one bh share one XCD's L2
// (8 bh x 512 KB = 4 MB). NO LDS, NO barriers, NO vmcnt: waves free-run and
// latency-hide each other (m169 precedent: de-stage L2-fit K/V).
__global__ __launch_bounds__(512, 4) void attn_fwd(const u16* __restrict__ qbuf,
                                                   const u16* __restrict__ ktiled,
                                                   const u16* __restrict__ vtiled,
                                                   u16* __restrict__ abuf) {
  const int tid = threadIdx.x;
  const int lane = tid & 63, wid = tid >> 6;   // 8 waves
  const int l32 = lane & 31, hl = lane >> 5;

  int bid = blockIdx.x;
  bid = (bid & 7) * 64 + (bid >> 3);   // T1 chunked XCD swizzle (512%8==0)
  const int bh = bid >> 3, qt = bid & 7;
  const int b = bh >> 4, h = bh & 15;
  const int q0 = qt * 256 + wid * 32;

  // ---- Q fragments (B-frag: col=q=l32, k=8*hl+j+16*step), scale 0.125*log2e ----
  constexpr float QS = SCALE_ * LOG2E_;
  bf16x8 qf[4];
  {
    const u16* qrow = qbuf + (size_t)(b * N_ + q0 + l32) * INNER_ + h * DH_ + hl * 8;
#pragma unroll
    for (int step = 0; step < 4; step++) {
      bf16x8 t = *(const bf16x8*)(qrow + step * 16);
#pragma unroll
      for (int i = 0; i < 8; i++) t[i] = (bf16_t)((float)t[i] * QS);
      qf[step] = t;
    }
  }

  const char* kbase = (const char*)(ktiled + (size_t)bh * 131072);
  const char* vbase = (const char*)(vtiled + (size_t)bh * 131072);
  // lane part of all fragment reads: hl selects odd slot, l32 the 16-B row entry
  const int kofs = (hl << 10) + (l32 << 4);

  float lrow = 0.f;
  f32x16 acc[2];
#pragma unroll
  for (int i = 0; i < 16; i++) { acc[0][i] = 0.f; acc[1][i] = 0.f; }

  const int NT = N_ / 64;
  for (int kt = 0; kt < NT; ++kt) {
    const char* Kb = kbase + kt * 8192;
    const char* Vb = vbase + kt * 8192;

    // ---- S^T = K @ Q : key = (reg&3)+8*(reg>>2)+4*hl+32*ktile, q = l32 ----
    f32x16 s[2];
    __builtin_amdgcn_s_setprio(1);
#pragma unroll
    for (int ktile = 0; ktile < 2; ktile++) {
      f32x16 c;
#pragma unroll
      for (int i = 0; i < 16; i++) c[i] = 0.f;
      const char* rb = Kb + (ktile << 9) + kofs;
#pragma unroll
      for (int step = 0; step < 4; step++) {
        bf16x8 kf = *(const bf16x8*)(rb + (step << 11));
        c = __builtin_amdgcn_mfma_f32_32x32x16_bf16(kf, qf[step], c, 0, 0, 0);
      }
      s[ktile] = c;
    }
    __builtin_amdgcn_s_setprio(0);

    // ---- softmax: p = exp2(S); lane-local, 2 psum chains for ILP ----
    float ps0 = 0.f, ps1 = 0.f;
#pragma unroll
    for (int ktile = 0; ktile < 2; ktile++)
#pragma unroll
      for (int i = 0; i < 16; i += 2) {
        const float p0 = EXP2F(s[ktile][i]);
        const float p1 = EXP2F(s[ktile][i + 1]);
        s[ktile][i] = p0; s[ktile][i + 1] = p1;
        ps0 += p0; ps1 += p1;
      }
    lrow += ps0 + ps1;

    // ---- in-register P -> PV B-frags (T12 permlane32_swap) ----
    bf16x8 pb[4];
#pragma unroll
    for (int ktile = 0; ktile < 2; ktile++)
#pragma unroll
      for (int par = 0; par < 2; par++) {
        const int rb8 = par * 8;
        const unsigned c0 = packbf(s[ktile][rb8 + 0], s[ktile][rb8 + 1]);
        const unsigned c1 = packbf(s[ktile][rb8 + 2], s[ktile][rb8 + 3]);
        const unsigned c2 = packbf(s[ktile][rb8 + 4], s[ktile][rb8 + 5]);
        const unsigned c3 = packbf(s[ktile][rb8 + 6], s[ktile][rb8 + 7]);
        const uint2v r02 = __builtin_amdgcn_permlane32_swap(c0, c2, false, false);
        const uint2v r13 = __builtin_amdgcn_permlane32_swap(c1, c3, false, false);
        union { unsigned u[4]; bf16x8 v; } w;
        w.u[0] = r02[0]; w.u[1] = r13[0]; w.u[2] = r02[1]; w.u[3] = r13[1];
        pb[ktile * 2 + par] = w.v;
      }

    // ---- O^T += V^T @ P ----
    __builtin_amdgcn_s_setprio(1);
#pragma unroll
    for (int dtile = 0; dtile < 2; dtile++) {
      const char* rb = Vb + (dtile << 9) + kofs;
      f32x16 c = acc[dtile];
#pragma unroll
      for (int step = 0; step < 4; step++) {
        bf16x8 vf = *(const bf16x8*)(rb + (step << 11));
        c = __builtin_amdgcn_mfma_f32_32x32x16_bf16(vf, pb[step], c, 0, 0, 0);
      }
      acc[dtile] = c;
    }
    __builtin_amdgcn_s_setprio(0);
  }

  // ---- epilogue: combine key-halves of l, normalize, 8 packed 8B stores ----
  lrow += __shfl_xor(lrow, 32);
  const float inv = 1.f / lrow;
  const size_t row = (size_t)(b * N_ + q0 + l32);
#pragma unroll
  for (int dtile = 0; dtile < 2; dtile++)
#pragma unroll
    for (int g = 0; g < 4; g++) {
      u16x4 w;
#pragma unroll
      for (int j = 0; j < 4; j++) w[j] = bfbits(acc[dtile][g * 4 + j] * inv);
      const int d = dtile * 32 + g * 8 + hl * 4;
      *(u16x4*)(abuf + row * INNER_ + h * DH_ + d) = w;
    }
}

extern "C" void kernel_launch(void* const* d_in, const int* in_sizes, int n_in,
                              void* d_out, int out_size, void* d_ws, size_t ws_size,
                              hipStream_t stream) {
  const float* x     = (const float*)d_in[0];
  const float* w_qkv = (const float*)d_in[1];
  const float* w_out = (const float*)d_in[2];
  const float* b_out = (const float*)d_in[3];
  float* out = (float*)d_out;

  char* ws = (char*)d_ws;
  u16* xb     = (u16*)(ws);                          // 16 MiB  [8192][1024]
  u16* wqkvT  = (u16*)(ws + (size_t)(16 << 20));     //  6 MiB  [3072][1024]
  u16* woutT  = (u16*)(ws + (size_t)(22 << 20));     //  2 MiB  [1024][1024]
  u16* qbuf   = (u16*)(ws + (size_t)(24 << 20));     // 16 MiB  [8192][1024]
  u16* ktiled = (u16*)(ws + (size_t)(40 << 20));     // 16 MiB  [64][32][8][64][8]
  u16* vtiled = (u16*)(ws + (size_t)(56 << 20));     // 16 MiB  [64][32][8][64][8]
  u16* abuf   = xb;  // alias: xb dead after gemm_qkv

  cvt_f32_bf16<<<4096, 256, 0, stream>>>(x, xb, (B_ * N_ * DIM_) / 8);
  transp_w<<<dim3(QKV3_ / 32, DIM_ / 32), 256, 0, stream>>>(w_qkv, wqkvT, DIM_, QKV3_);
  transp_w<<<dim3(DIM_ / 32, INNER_ / 32), 256, 0, stream>>>(w_out, woutT, INNER_, DIM_);
  gemm_qkv<<<(B_ * N_ / 128) * (QKV3_ / 128), 256, 0, stream>>>(
      xb, wqkvT, qbuf, ktiled, vtiled, B_ * N_, QKV3_, DIM_);
  attn_fwd<<<512, 512, 0, stream>>>(qbuf, ktiled, vtiled, abuf);
  gemm_bt<<<(B_ * N_ / 128) * (DIM_ / 128), 256, 0, stream>>>(
      abuf, woutT, out, b_out, B_ * N_, DIM_, INNER_);
}

// Round 13
// 188.317 us; speedup vs baseline: 1.1289x; 1.1289x over previous
//
#include <hip/hip_runtime.h>

typedef unsigned short u16;
typedef __bf16 bf16_t;
typedef bf16_t bf16x8 __attribute__((ext_vector_type(8)));
typedef float f32x4 __attribute__((ext_vector_type(4)));
typedef float f32x16 __attribute__((ext_vector_type(16)));
typedef u16 u16x8 __attribute__((ext_vector_type(8)));
typedef u16 u16x4 __attribute__((ext_vector_type(4)));
typedef unsigned uint2v __attribute__((ext_vector_type(2)));

#define B_     4
#define N_     2048
#define DIM_   1024
#define HEADS_ 16
#define DH_    64
#define INNER_ 1024
#define QKV3_  3072
#define SCALE_ 0.125f
#define LOG2E_ 1.44269504089f

__device__ __forceinline__ u16 f2bf(float f) {
  union { float f; unsigned u; } v; v.f = f;
  unsigned r = v.u + 0x7FFFu + ((v.u >> 16) & 1u);
  return (u16)(r >> 16);
}
__device__ __forceinline__ u16 bfbits(float f) {
  bf16_t b = (bf16_t)f;               // RNE; pairs into v_cvt_pk_bf16_f32
  return __builtin_bit_cast(u16, b);
}
__device__ __forceinline__ unsigned packbf(float lo, float hi) {
  return (unsigned)bfbits(lo) | ((unsigned)bfbits(hi) << 16);
}

#if __has_builtin(__builtin_amdgcn_exp2f)
#define EXP2F(x) __builtin_amdgcn_exp2f(x)
#else
#define EXP2F(x) __expf((x) * 0.69314718056f)
#endif

// async global->LDS, 16B per lane; LDS dest = wave-uniform base + lane*16
typedef __attribute__((address_space(1))) const unsigned int ga_u32;
typedef __attribute__((address_space(3))) unsigned int ls_u32;
__device__ __forceinline__ void gload16(const void* g, void* l) {
  __builtin_amdgcn_global_load_lds((ga_u32*)g, (ls_u32*)l, 16, 0, 0);
}

// ---------------- x fp32 -> bf16 (vectorized, G13) ----------------
__global__ __launch_bounds__(256) void cvt_f32_bf16(const float* __restrict__ in,
                                                    u16* __restrict__ out, int n8) {
  int i = blockIdx.x * 256 + threadIdx.x;
  if (i < n8) {
    const float4* p = (const float4*)(in + (size_t)i * 8);
    float4 a = p[0], b = p[1];
    u16x8 o;
    o[0] = f2bf(a.x); o[1] = f2bf(a.y); o[2] = f2bf(a.z); o[3] = f2bf(a.w);
    o[4] = f2bf(b.x); o[5] = f2bf(b.y); o[6] = f2bf(b.z); o[7] = f2bf(b.w);
    *(u16x8*)(out + (size_t)i * 8) = o;
  }
}

// ---------------- w [K][N] fp32 -> wT [N][K] bf16 ----------------
__global__ __launch_bounds__(256) void transp_w(const float* __restrict__ in,
                                                u16* __restrict__ out, int Kd, int Nd) {
  __shared__ float t[32][33];
  int n0 = blockIdx.x * 32, k0 = blockIdx.y * 32;
  int tx = threadIdx.x & 31, ty = threadIdx.x >> 5;   // 256 threads: 32x8
#pragma unroll
  for (int i = 0; i < 4; i++)
    t[ty + i * 8][tx] = in[(size_t)(k0 + ty + i * 8) * Nd + n0 + tx];
  __syncthreads();
#pragma unroll
  for (int i = 0; i < 4; i++)
    out[(size_t)(n0 + ty + i * 8) * Kd + k0 + tx] = f2bf(t[tx][ty + i * 8]);
}

// ---------------- fused QKV GEMM v2: 256x384 tile, BK=32, 3-buffer rotation ----------------
// 512 thr / 8 waves (2M x 4N); per-wave 128x96 output = 8mf x 6nf frags.
// LDS-reads/MFMA = 14/48 = 0.29 (vs 0.5 at 128^2) -> LDS pipe no longer the cap.
// 3 LDS buffers (120 KB, 1 block/CU), counted vmcnt(5), ONE barrier per K-step,
// stage ks+2 after the barrier (attn-v9-proven rotation; lag-2 latency cover).
// Grid 256 = 32x8: exactly 1 block/CU, tail-free. 64-B LDS rows, swizzle
// byte ^= (row&3)<<4 with pre-swizzled source (bijective; bandwidth-floor only).
// Epilogue scatters Q plain, K/V slot-major tiled (conflict-free attn reads).
__global__ __launch_bounds__(512, 2) void gemm_qkv(const u16* __restrict__ A,
                                                   const u16* __restrict__ BT,
                                                   u16* __restrict__ qbuf,
                                                   u16* __restrict__ ktiled,
                                                   u16* __restrict__ vtiled) {
  constexpr int K = DIM_;          // 1024
  constexpr int KS = K / 32;       // 32 K-steps
  __shared__ alignas(16) u16 ldsA[3][256 * 32];   // 48 KB
  __shared__ alignas(16) u16 ldsB[3][384 * 32];   // 72 KB
  const int tid = threadIdx.x;
  const int lane = tid & 63, wid = tid >> 6;      // 8 waves
  const int l16 = lane & 15, lg = lane >> 4;
  const int wm = wid >> 2, wn = wid & 3;          // 2M x 4N

  int bid = blockIdx.x;                            // grid 256 = 32 tm x 8 tn
  bid = (bid & 7) * 32 + (bid >> 3);               // bijective XCD swizzle
  const int tm = bid >> 3, tn = bid & 7;
  const int m0 = tm << 8, n0 = tn * 384;

  // staging: per gload16 instr, 512 thr cover 128 rows x 32 cols (8 KB)
  const int srow = tid >> 2;                       // 0..127
  const int soff = ((tid & 3) ^ (srow & 3)) * 8;   // pre-swizzled source slot (elems)
  const u16* Asrc = A  + (size_t)(m0 + srow) * K + soff;
  const u16* Bsrc = BT + (size_t)(n0 + srow) * K + soff;
  const int sdst = wid << 10;                      // wave-uniform byte offset

  f32x4 acc[8][6];
#pragma unroll
  for (int i = 0; i < 8; i++)
#pragma unroll
    for (int j = 0; j < 6; j++) acc[i][j] = f32x4{0.f, 0.f, 0.f, 0.f};

#define STG_(kk, buf)                                                        \
  do {                                                                       \
    const int kb_ = (kk) << 5;                                               \
    gload16(Asrc + kb_,                 (char*)&ldsA[(buf)][0] + sdst);      \
    gload16(Asrc + (size_t)128 * K + kb_, (char*)&ldsA[(buf)][0] + 8192 + sdst); \
    gload16(Bsrc + kb_,                 (char*)&ldsB[(buf)][0] + sdst);      \
    gload16(Bsrc + (size_t)128 * K + kb_, (char*)&ldsB[(buf)][0] + 8192 + sdst); \
    gload16(Bsrc + (size_t)256 * K + kb_, (char*)&ldsB[(buf)][0] + 16384 + sdst);\
  } while (0)

  STG_(0, 0);
  STG_(1, 1);

  int cur = 0, pre = 2;
  for (int ks = 0; ks < KS; ks++) {
    if (ks < KS - 1) asm volatile("s_waitcnt vmcnt(5)" ::: "memory");
    else             asm volatile("s_waitcnt vmcnt(0)" ::: "memory");
    __builtin_amdgcn_s_barrier();
    if (ks + 2 < KS) STG_(ks + 2, pre);

    const char* cA = (const char*)&ldsA[cur][0];
    const char* cB = (const char*)&ldsB[cur][0];

    // B-frags once per step (6 reads), A streamed per mf (8 reads)
    bf16x8 bf[6];
#pragma unroll
    for (int nf = 0; nf < 6; nf++) {
      const int row = wn * 96 + nf * 16 + l16;
      bf[nf] = *(const bf16x8*)(cB + row * 64 + ((lg * 16) ^ ((row & 3) << 4)));
    }
    __builtin_amdgcn_s_setprio(1);
#pragma unroll
    for (int mf = 0; mf < 8; mf++) {
      const int row = wm * 128 + mf * 16 + l16;
      bf16x8 af = *(const bf16x8*)(cA + row * 64 + ((lg * 16) ^ ((row & 3) << 4)));
#pragma unroll
      for (int nf = 0; nf < 6; nf++)
        acc[mf][nf] = __builtin_amdgcn_mfma_f32_16x16x32_bf16(af, bf[nf], acc[mf][nf], 0, 0, 0);
    }
    __builtin_amdgcn_s_setprio(0);

    cur = (cur == 2) ? 0 : cur + 1;
    pre = (pre == 2) ? 0 : pre + 1;
  }
#undef STG_

  // epilogue: seg uniform per (wn,nf) since 16 | 1024
#pragma unroll
  for (int mf = 0; mf < 8; mf++) {
#pragma unroll
    for (int nf = 0; nf < 6; nf++) {
      const int row = m0 + wm * 128 + mf * 16 + lg * 4;
      const int col = n0 + wn * 96 + nf * 16 + l16;
      const int seg = (n0 + wn * 96 + nf * 16) >> 10;
      if (seg == 0) {
#pragma unroll
        for (int j = 0; j < 4; j++)
          qbuf[(size_t)(row + j) * INNER_ + col] = f2bf(acc[mf][nf][j]);
      } else if (seg == 1) {
        const int kd = col - 1024;
        const int h = kd >> 6, s = (kd >> 3) & 7, e = kd & 7;
#pragma unroll
        for (int j = 0; j < 4; j++) {
          const int rr = row + j;
          const int b = rr >> 11, n = rr & (N_ - 1);
          ktiled[(((size_t)(b * HEADS_ + h) * 32 + (n >> 6)) << 12) +
                 (s << 9) + ((n & 63) << 3) + e] = f2bf(acc[mf][nf][j]);
        }
      } else {
        const int vd = col - 2048;
        const int h = vd >> 6, d = vd & 63;
#pragma unroll
        for (int j = 0; j < 4; j++) {
          const int rr = row + j;
          const int b = rr >> 11, n = rr & (N_ - 1);
          vtiled[(((size_t)(b * HEADS_ + h) * 32 + (n >> 6)) << 12) +
                 (((n >> 3) & 7) << 9) + (d << 3) + (n & 7)] = f2bf(acc[mf][nf][j]);
        }
      }
    }
  }
}

// ---------------- GEMM2: C[M][N] = A @ BT^T + bias (f32 out), 128^2 tile ----------------
__global__ __launch_bounds__(256) void gemm_bt(const u16* __restrict__ A,
                                               const u16* __restrict__ BT,
                                               float* __restrict__ Cp,
                                               const float* __restrict__ bias,
                                               int M, int N, int K) {
  __shared__ alignas(16) u16 ldsA[2][128 * 64];
  __shared__ alignas(16) u16 ldsB[2][128 * 64];
  const int tid = threadIdx.x;
  const int lane = tid & 63, wid = tid >> 6;
  const int l16 = lane & 15, lg = lane >> 4;

  int bid = blockIdx.x;
  const int cpx = gridDim.x >> 3;
  bid = (bid & 7) * cpx + (bid >> 3);

  const int ntiles = N >> 7;
  const int tm = bid / ntiles, tn = bid % ntiles;
  const int m0 = tm << 7, n0 = tn << 7;
  const int wr = wid >> 1, wc = wid & 1;

  const int srow_in = lane >> 3;
  const int soff = ((lane & 7) ^ srow_in) * 8;

  f32x4 acc[4][4];
#pragma unroll
  for (int i = 0; i < 4; i++)
#pragma unroll
    for (int j = 0; j < 4; j++) acc[i][j] = f32x4{0.f, 0.f, 0.f, 0.f};

  const int KSTEPS = K >> 6;

#define GSTAGE_(kk, buf)                                                           \
  do {                                                                             \
    const int k1_ = (kk) << 6;                                                     \
    char* bA_ = (char*)&ldsA[(buf)][0];                                            \
    char* bB_ = (char*)&ldsB[(buf)][0];                                            \
    _Pragma("unroll")                                                              \
    for (int i_ = 0; i_ < 4; i_++) {                                               \
      const int rb_ = wid * 32 + i_ * 8;                                           \
      gload16(A  + (size_t)(m0 + rb_ + srow_in) * K + k1_ + soff, bA_ + rb_ * 128);\
      gload16(BT + (size_t)(n0 + rb_ + srow_in) * K + k1_ + soff, bB_ + rb_ * 128);\
    }                                                                              \
  } while (0)

  GSTAGE_(0, 0);
  GSTAGE_(1, 1);

  for (int ks = 0; ks < KSTEPS; ks++) {
    if (ks + 1 < KSTEPS) asm volatile("s_waitcnt vmcnt(8)" ::: "memory");
    else                 asm volatile("s_waitcnt vmcnt(0)" ::: "memory");
    __builtin_amdgcn_s_barrier();

    const char* cA = (const char*)&ldsA[ks & 1][0];
    const char* cB = (const char*)&ldsB[ks & 1][0];

    bf16x8 bf[4][2];
#pragma unroll
    for (int n = 0; n < 4; n++) {
      int row = wc * 64 + n * 16 + l16;
      int rb = row * 128, swz = (row & 7) << 4;
      bf[n][0] = *(const bf16x8*)(cB + rb + ((lg * 16) ^ swz));
      bf[n][1] = *(const bf16x8*)(cB + rb + ((64 + lg * 16) ^ swz));
    }
    __builtin_amdgcn_s_setprio(1);
#pragma unroll
    for (int mm = 0; mm < 4; mm++) {
      int row = wr * 64 + mm * 16 + l16;
      int rb = row * 128, swz = (row & 7) << 4;
      bf16x8 af0 = *(const bf16x8*)(cA + rb + ((lg * 16) ^ swz));
      bf16x8 af1 = *(const bf16x8*)(cA + rb + ((64 + lg * 16) ^ swz));
#pragma unroll
      for (int n = 0; n < 4; n++) {
        acc[mm][n] = __builtin_amdgcn_mfma_f32_16x16x32_bf16(af0, bf[n][0], acc[mm][n], 0, 0, 0);
        acc[mm][n] = __builtin_amdgcn_mfma_f32_16x16x32_bf16(af1, bf[n][1], acc[mm][n], 0, 0, 0);
      }
    }
    __builtin_amdgcn_s_setprio(0);

    __builtin_amdgcn_s_barrier();
    if (ks + 2 < KSTEPS) GSTAGE_(ks + 2, ks & 1);
  }
#undef GSTAGE_

#pragma unroll
  for (int mm = 0; mm < 4; mm++) {
#pragma unroll
    for (int n = 0; n < 4; n++) {
      int row = m0 + wr * 64 + mm * 16 + lg * 4;
      int col = n0 + wc * 64 + n * 16 + l16;
#pragma unroll
      for (int j = 0; j < 4; j++)
        Cp[(size_t)(row + j) * N + col] = acc[mm][n][j] + bias[col];
    }
  }
}

// ---------------- Flash attention (v9, REVERTED: slot-major K/V tiles, staged LDS) ----------------
// 512 blocks (XCD-swizzled) x 512 threads (8 waves). Wave owns 32 q; QBLK=256.
// K/V pre-tiled in global (by gemm_qkv epilogue) as [bh][kt][slot][row][8] -> staging is
// 1 linear 1-KB gload16 per wave per tensor; every fragment ds_read_b128 is stride-1
// across lanes (conflict-free measured). Q pre-scaled by 0.125*log2e -> p = exp2(S).
// In-register P via cvt_pk+permlane32_swap. 3-buffer K/V, counted vmcnt(2), 1 barrier/kt.
__global__ __launch_bounds__(512, 4) void attn_fwd(const u16* __restrict__ qbuf,
                                                   const u16* __restrict__ ktiled,
                                                   const u16* __restrict__ vtiled,
                                                   u16* __restrict__ abuf) {
  __shared__ alignas(16) u16 ldsK[3][64 * 64];
  __shared__ alignas(16) u16 ldsV[3][64 * 64];

  const int tid = threadIdx.x;
  const int lane = tid & 63, wid = tid >> 6;   // 8 waves
  const int l32 = lane & 31, hl = lane >> 5;

  int bid = blockIdx.x;
  bid = (bid & 7) * 64 + (bid >> 3);   // T1 chunked XCD swizzle (512%8==0)
  const int bh = bid >> 3, qt = bid & 7;
  const int b = bh >> 4, h = bh & 15;
  const int q0 = qt * 256 + wid * 32;

  constexpr float QS = SCALE_ * LOG2E_;
  bf16x8 qf[4];
  {
    const u16* qrow = qbuf + (size_t)(b * N_ + q0 + l32) * INNER_ + h * DH_ + hl * 8;
#pragma unroll
    for (int step = 0; step < 4; step++) {
      bf16x8 t = *(const bf16x8*)(qrow + step * 16);
#pragma unroll
      for (int i = 0; i < 8; i++) t[i] = (bf16_t)((float)t[i] * QS);
      qf[step] = t;
    }
  }

  const u16* kts = ktiled + (size_t)bh * 131072 + tid * 8;
  const u16* vts = vtiled + (size_t)bh * 131072 + tid * 8;
  const int sdst = wid << 10;

  const int kofs = (hl << 10) + (l32 << 4);

  float lrow = 0.f;
  f32x16 acc[2];
#pragma unroll
  for (int i = 0; i < 16; i++) { acc[0][i] = 0.f; acc[1][i] = 0.f; }

  gload16(kts, (char*)ldsK + sdst);
  gload16(vts, (char*)ldsV + sdst);
  gload16(kts + 4096, (char*)ldsK + 8192 + sdst);
  gload16(vts + 4096, (char*)ldsV + 8192 + sdst);

  const int NT = N_ / 64;
  int cur = 0, pre = 2;

  for (int kt = 0; kt < NT; ++kt) {
    if (kt < NT - 1) asm volatile("s_waitcnt vmcnt(2)" ::: "memory");
    else             asm volatile("s_waitcnt vmcnt(0)" ::: "memory");
    __builtin_amdgcn_s_barrier();
    if (kt + 2 < NT) {
      gload16(kts + (size_t)(kt + 2) * 4096, (char*)ldsK + pre * 8192 + sdst);
      gload16(vts + (size_t)(kt + 2) * 4096, (char*)ldsV + pre * 8192 + sdst);
    }

    const char* Kb = (const char*)ldsK + cur * 8192;
    const char* Vb = (const char*)ldsV + cur * 8192;

    f32x16 s[2];
    __builtin_amdgcn_s_setprio(1);
#pragma unroll
    for (int ktile = 0; ktile < 2; ktile++) {
      f32x16 c;
#pragma unroll
      for (int i = 0; i < 16; i++) c[i] = 0.f;
      const char* rb = Kb + (ktile << 9) + kofs;
#pragma unroll
      for (int step = 0; step < 4; step++) {
        bf16x8 kf = *(const bf16x8*)(rb + (step << 11));
        c = __builtin_amdgcn_mfma_f32_32x32x16_bf16(kf, qf[step], c, 0, 0, 0);
      }
      s[ktile] = c;
    }
    __builtin_amdgcn_s_setprio(0);

    float ps0 = 0.f, ps1 = 0.f;
#pragma unroll
    for (int ktile = 0; ktile < 2; ktile++)
#pragma unroll
      for (int i = 0; i < 16; i += 2) {
        const float p0 = EXP2F(s[ktile][i]);
        const float p1 = EXP2F(s[ktile][i + 1]);
        s[ktile][i] = p0; s[ktile][i + 1] = p1;
        ps0 += p0; ps1 += p1;
      }
    lrow += ps0 + ps1;

    bf16x8 pb[4];
#pragma unroll
    for (int ktile = 0; ktile < 2; ktile++)
#pragma unroll
      for (int par = 0; par < 2; par++) {
        const int rb8 = par * 8;
        const unsigned c0 = packbf(s[ktile][rb8 + 0], s[ktile][rb8 + 1]);
        const unsigned c1 = packbf(s[ktile][rb8 + 2], s[ktile][rb8 + 3]);
        const unsigned c2 = packbf(s[ktile][rb8 + 4], s[ktile][rb8 + 5]);
        const unsigned c3 = packbf(s[ktile][rb8 + 6], s[ktile][rb8 + 7]);
        const uint2v r02 = __builtin_amdgcn_permlane32_swap(c0, c2, false, false);
        const uint2v r13 = __builtin_amdgcn_permlane32_swap(c1, c3, false, false);
        union { unsigned u[4]; bf16x8 v; } w;
        w.u[0] = r02[0]; w.u[1] = r13[0]; w.u[2] = r02[1]; w.u[3] = r13[1];
        pb[ktile * 2 + par] = w.v;
      }

    __builtin_amdgcn_s_setprio(1);
#pragma unroll
    for (int dtile = 0; dtile < 2; dtile++) {
      const char* rb = Vb + (dtile << 9) + kofs;
      f32x16 c = acc[dtile];
#pragma unroll
      for (int step = 0; step < 4; step++) {
        bf16x8 vf = *(const bf16x8*)(rb + (step << 11));
        c = __builtin_amdgcn_mfma_f32_32x32x16_bf16(vf, pb[step], c, 0, 0, 0);
      }
      acc[dtile] = c;
    }
    __builtin_amdgcn_s_setprio(0);

    cur = (cur == 2) ? 0 : cur + 1;
    pre = (pre == 2) ? 0 : pre + 1;
  }

  lrow += __shfl_xor(lrow, 32);
  const float inv = 1.f / lrow;
  const size_t row = (size_t)(b * N_ + q0 + l32);
#pragma unroll
  for (int dtile = 0; dtile < 2; dtile++)
#pragma unroll
    for (int g = 0; g < 4; g++) {
      u16x4 w;
#pragma unroll
      for (int j = 0; j < 4; j++) w[j] = bfbits(acc[dtile][g * 4 + j] * inv);
      const int d = dtile * 32 + g * 8 + hl * 4;
      *(u16x4*)(abuf + row * INNER_ + h * DH_ + d) = w;
    }
}

extern "C" void kernel_launch(void* const* d_in, const int* in_sizes, int n_in,
                              void* d_out, int out_size, void* d_ws, size_t ws_size,
                              hipStream_t stream) {
  const float* x     = (const float*)d_in[0];
  const float* w_qkv = (const float*)d_in[1];
  const float* w_out = (const float*)d_in[2];
  const float* b_out = (const float*)d_in[3];
  float* out = (float*)d_out;

  char* ws = (char*)d_ws;
  u16* xb     = (u16*)(ws);                          // 16 MiB  [8192][1024]
  u16* wqkvT  = (u16*)(ws + (size_t)(16 << 20));     //  6 MiB  [3072][1024]
  u16* woutT  = (u16*)(ws + (size_t)(22 << 20));     //  2 MiB  [1024][1024]
  u16* qbuf   = (u16*)(ws + (size_t)(24 << 20));     // 16 MiB  [8192][1024]
  u16* ktiled = (u16*)(ws + (size_t)(40 << 20));     // 16 MiB  [64][32][8][64][8]
  u16* vtiled = (u16*)(ws + (size_t)(56 << 20));     // 16 MiB  [64][32][8][64][8]
  u16* abuf   = xb;  // alias: xb dead after gemm_qkv

  cvt_f32_bf16<<<4096, 256, 0, stream>>>(x, xb, (B_ * N_ * DIM_) / 8);
  transp_w<<<dim3(QKV3_ / 32, DIM_ / 32), 256, 0, stream>>>(w_qkv, wqkvT, DIM_, QKV3_);
  transp_w<<<dim3(DIM_ / 32, INNER_ / 32), 256, 0, stream>>>(w_out, woutT, INNER_, DIM_);
  gemm_qkv<<<256, 512, 0, stream>>>(xb, wqkvT, qbuf, ktiled, vtiled);
  attn_fwd<<<512, 512, 0, stream>>>(qbuf, ktiled, vtiled, abuf);
  gemm_bt<<<(B_ * N_ / 128) * (DIM_ / 128), 256, 0, stream>>>(
      abuf, woutT, out, b_out, B_ * N_, DIM_, INNER_);
}